// Round 1
// baseline (1792.113 us; speedup 1.0000x reference)
//
#include <hip/hip_runtime.h>

#define NN 50000
#define EE 800000
#define TILE 64
#define NTILES (EE / TILE)          // 12500
#define BLOCKS_PER_GRAPH 512

// order-preserving float->u32 encoding for atomicMax-based scatter-max
__device__ __forceinline__ unsigned enc(float f) {
    unsigned u = __float_as_uint(f);
    return (u & 0x80000000u) ? ~u : (u | 0x80000000u);
}
__device__ __forceinline__ float dec(unsigned u) {
    unsigned v = (u & 0x80000000u) ? (u & 0x7FFFFFFFu) : ~u;
    return __uint_as_float(v);
}

__global__ void init_acc(unsigned* __restrict__ acc, int n) {
    int i = blockIdx.x * blockDim.x + threadIdx.x;
    if (i < n) acc[i] = 0u;   // 0 < encoding of any finite float; marks "empty"
}

__global__ void decode_acc(unsigned* __restrict__ acc, int n) {
    int i = blockIdx.x * blockDim.x + threadIdx.x;
    if (i < n) {
        unsigned u = acc[i];
        float f = (u == 0u) ? 0.0f : dec(u);   // empty segment -> 0.0 (ref semantics)
        ((float*)acc)[i] = f;
    }
}

// One kernel handles both graphs: blocks [0,512) -> graph0, [512,1024) -> graph1.
// Per 64-edge tile: gather eT[128][64] -> GEMM1 (relu) -> hT[128][64] -> GEMM2
// -> encoded atomicMax scatter into acc[row*128 + 64*g + c].
__global__ __launch_bounds__(512, 2)
void edge_mlp(const float* __restrict__ x1, const float* __restrict__ x2,
              const int* __restrict__ ei1, const int* __restrict__ ei2,
              const float* __restrict__ W1, const float* __restrict__ b1,
              const float* __restrict__ W2, const float* __restrict__ b2,
              unsigned* __restrict__ acc)
{
    __shared__ float sW1[128 * 128];   // 64 KB, row-major [k][j]
    __shared__ float sW2[128 * 64];    // 32 KB, row-major [j][c]
    __shared__ float sb1[128];
    __shared__ float sb2[64];
    __shared__ float buf[128 * 64];    // 32 KB: eT then hT, [k][edge]
    __shared__ int   srow[64];
    __shared__ int   scol[64];

    const int tid = threadIdx.x;
    const int g = (blockIdx.x >= BLOCKS_PER_GRAPH) ? 1 : 0;
    const int bslot = blockIdx.x & (BLOCKS_PER_GRAPH - 1);
    const int* __restrict__ ei = g ? ei2 : ei1;
    const float* __restrict__ xc = g ? x2 : x1;
    const int goff = g * 64;

    // stage weights + biases (once per block)
    {
        const float4* w1v = (const float4*)W1;
        float4* s1v = (float4*)sW1;
        for (int i = tid; i < 4096; i += 512) s1v[i] = w1v[i];
        const float4* w2v = (const float4*)W2;
        float4* s2v = (float4*)sW2;
        for (int i = tid; i < 2048; i += 512) s2v[i] = w2v[i];
        if (tid < 128) sb1[tid] = b1[tid];
        if (tid < 64)  sb2[tid] = b2[tid];
    }

    const int eg = tid & 15;    // edge group: edges 4*eg .. 4*eg+3
    const int cg = tid >> 4;    // layer1: channels 4*cg..+3 ; layer2: channels 2*cg..+1

    for (int tile = bslot; tile < NTILES; tile += BLOCKS_PER_GRAPH) {
        const int ebase = tile * TILE;
        __syncthreads();   // protect buf/srow/scol from previous iteration
        if (tid < 64) {
            srow[tid] = ei[ebase + tid];
            scol[tid] = ei[EE + ebase + tid];
        }
        __syncthreads();

        // gather edge features, transposed: buf[k][e], k in [0,128)
        for (int i = tid; i < 64 * 32; i += 512) {
            int e = i & 63;
            int c = i >> 6;              // 16B feature chunk, 0..31
            int r = srow[e];
            float4 v;
            if (c < 16) {                // p = x1[row][0..63]
                v = ((const float4*)(x1 + (size_t)r * 64))[c];
            } else {                     // q = xc[col] - x1[row], features 64..127
                int cc = c - 16;
                float4 a = ((const float4*)(x1 + (size_t)r * 64))[cc];
                float4 b = ((const float4*)(xc + (size_t)scol[e] * 64))[cc];
                v = make_float4(b.x - a.x, b.y - a.y, b.z - a.z, b.w - a.w);
            }
            int k0 = c * 4;
            buf[(k0 + 0) * 64 + e] = v.x;
            buf[(k0 + 1) * 64 + e] = v.y;
            buf[(k0 + 2) * 64 + e] = v.z;
            buf[(k0 + 3) * 64 + e] = v.w;
        }
        __syncthreads();

        // ---- layer 1: h[4 edges][4 ch] = eT @ W1 + b1, relu ----
        float h[4][4];
        #pragma unroll
        for (int ee = 0; ee < 4; ++ee)
            #pragma unroll
            for (int jj = 0; jj < 4; ++jj)
                h[ee][jj] = sb1[4 * cg + jj];

        #pragma unroll 4
        for (int k = 0; k < 128; ++k) {
            float a[4], w[4];
            *(float4*)a = *(const float4*)&buf[k * 64 + 4 * eg];
            *(float4*)w = *(const float4*)&sW1[k * 128 + 4 * cg];
            #pragma unroll
            for (int ee = 0; ee < 4; ++ee)
                #pragma unroll
                for (int jj = 0; jj < 4; ++jj)
                    h[ee][jj] = fmaf(a[ee], w[jj], h[ee][jj]);
        }

        __syncthreads();   // all eT reads done before overwriting buf with hT

        // write hT[k=channel][edge] with relu
        #pragma unroll
        for (int jj = 0; jj < 4; ++jj)
            #pragma unroll
            for (int ee = 0; ee < 4; ++ee)
                buf[(4 * cg + jj) * 64 + 4 * eg + ee] = fmaxf(h[ee][jj], 0.0f);
        __syncthreads();

        // ---- layer 2: o[4 edges][2 ch] = hT @ W2 + b2 ----
        float o[4][2];
        #pragma unroll
        for (int ee = 0; ee < 4; ++ee) {
            o[ee][0] = sb2[2 * cg + 0];
            o[ee][1] = sb2[2 * cg + 1];
        }
        #pragma unroll 4
        for (int k = 0; k < 128; ++k) {
            float a[4];
            *(float4*)a = *(const float4*)&buf[k * 64 + 4 * eg];
            float2 wv = *(const float2*)&sW2[k * 64 + 2 * cg];
            #pragma unroll
            for (int ee = 0; ee < 4; ++ee) {
                o[ee][0] = fmaf(a[ee], wv.x, o[ee][0]);
                o[ee][1] = fmaf(a[ee], wv.y, o[ee][1]);
            }
        }

        // ---- scatter-max ----
        #pragma unroll
        for (int ee = 0; ee < 4; ++ee) {
            int r = srow[4 * eg + ee];
            unsigned* dst = acc + (size_t)r * 128 + goff + 2 * cg;
            atomicMax(dst,     enc(o[ee][0]));
            atomicMax(dst + 1, enc(o[ee][1]));
        }
    }
}

extern "C" void kernel_launch(void* const* d_in, const int* in_sizes, int n_in,
                              void* d_out, int out_size, void* d_ws, size_t ws_size,
                              hipStream_t stream) {
    const float* x1 = (const float*)d_in[0];
    const float* x2 = (const float*)d_in[1];
    const int*   ei1 = (const int*)d_in[2];
    const int*   ei2 = (const int*)d_in[3];
    const float* W1 = (const float*)d_in[4];
    const float* b1 = (const float*)d_in[5];
    const float* W2 = (const float*)d_in[6];
    const float* b2 = (const float*)d_in[7];
    unsigned* acc = (unsigned*)d_out;   // accumulate in-place in d_out as u32

    const int total = NN * 128;
    hipLaunchKernelGGL(init_acc, dim3((total + 255) / 256), dim3(256), 0, stream,
                       acc, total);
    hipLaunchKernelGGL(edge_mlp, dim3(2 * BLOCKS_PER_GRAPH), dim3(512), 0, stream,
                       x1, x2, ei1, ei2, W1, b1, W2, b2, acc);
    hipLaunchKernelGGL(decode_acc, dim3((total + 255) / 256), dim3(256), 0, stream,
                       acc, total);
}

// Round 2
// 386.589 us; speedup vs baseline: 4.6357x; 4.6357x over previous
//
#include <hip/hip_runtime.h>

#define NN 50000
#define EE 800000
#define TILE 64
#define NTILES (EE / TILE)          // 12500
#define BPG 512                     // blocks per graph

typedef __attribute__((ext_vector_type(8))) short bf16x8;
typedef __attribute__((ext_vector_type(4))) float f32x4;

// order-preserving float->u32 encoding for atomicMax-based scatter-max
__device__ __forceinline__ unsigned enc(float f) {
    unsigned u = __float_as_uint(f);
    return (u & 0x80000000u) ? ~u : (u | 0x80000000u);
}
__device__ __forceinline__ float dec(unsigned u) {
    unsigned v = (u & 0x80000000u) ? (u & 0x7FFFFFFFu) : ~u;
    return __uint_as_float(v);
}

__device__ __forceinline__ unsigned short f2bf(float f) {   // RNE bf16
    unsigned u = __float_as_uint(f);
    u += 0x7fffu + ((u >> 16) & 1u);
    return (unsigned short)(u >> 16);
}
__device__ __forceinline__ unsigned pk2(float a, float b) { // [a | b<<16]
    return (unsigned)f2bf(a) | ((unsigned)f2bf(b) << 16);
}

__global__ void init_acc(unsigned* __restrict__ acc, int n) {
    int i = blockIdx.x * blockDim.x + threadIdx.x;
    if (i < n) acc[i] = 0u;   // 0 < enc(any finite float); marks "empty"
}

__global__ void decode_acc(unsigned* __restrict__ acc, int n) {
    int i = blockIdx.x * blockDim.x + threadIdx.x;
    if (i < n) {
        unsigned u = acc[i];
        ((float*)acc)[i] = (u == 0u) ? 0.0f : dec(u);   // empty -> 0.0 (ref)
    }
}

// 256 threads = 4 waves. Wave (w_h, w_e): w_h = hid/out half, w_e = edge half.
// Per 64-edge tile:
//   gather -> e_lds[edge][128] bf16 (swizzled)
//   L1: hT-frags = mfma(W1T regs, e frags) -> relu -> h_lds[edge][128] bf16
//   L2: o-frags  = mfma(h frags, W2 regs)  -> enc+atomicMax scatter
__global__ __launch_bounds__(256, 2)
void edge_mlp(const float* __restrict__ x1, const float* __restrict__ x2,
              const int* __restrict__ ei1, const int* __restrict__ ei2,
              const float* __restrict__ W1, const float* __restrict__ b1,
              const float* __restrict__ W2, const float* __restrict__ b2,
              unsigned* __restrict__ acc)
{
    __shared__ short e_lds[64 * 128];   // 16 KB
    __shared__ short h_lds[64 * 128];   // 16 KB
    __shared__ int   srow[64];
    __shared__ int   scol[64];

    const int tid  = threadIdx.x;
    const int lane = tid & 63;
    const int l15  = lane & 15;
    const int lg   = lane >> 4;         // 0..3
    const int wid  = tid >> 6;
    const int w_h  = wid & 1;           // hid/out half owner
    const int w_e  = wid >> 1;          // edge half owner

    const int g     = (blockIdx.x >= BPG) ? 1 : 0;
    const int bslot = blockIdx.x & (BPG - 1);
    const int* __restrict__ ei = g ? ei2 : ei1;
    const float* __restrict__ xc = g ? x2 : x1;
    const int goff = g * 64;

    // ---- persistent register weights ----
    // A1-frags of W1^T: lane l -> W1T[hid0+16m+l15][32s+8lg+i] = W1[k][hid]
    bf16x8 a1[4][4];                    // [m: hid frag][s: kstep]
    #pragma unroll
    for (int m = 0; m < 4; ++m)
        #pragma unroll
        for (int s = 0; s < 4; ++s) {
            const float* p = W1 + (size_t)(32 * s + 8 * lg) * 128
                               + (w_h * 64 + 16 * m + l15);
            bf16x8 r;
            #pragma unroll
            for (int i = 0; i < 8; ++i) r[i] = (short)f2bf(p[i * 128]);
            a1[m][s] = r;
        }
    // B2-frags of W2: lane l -> W2[32s+8lg+i][out0+16n+l15]
    bf16x8 b2f[4][2];                   // [s: kstep][n: out frag]
    #pragma unroll
    for (int s = 0; s < 4; ++s)
        #pragma unroll
        for (int n = 0; n < 2; ++n) {
            const float* p = W2 + (size_t)(32 * s + 8 * lg) * 64
                               + (w_h * 32 + 16 * n + l15);
            bf16x8 r;
            #pragma unroll
            for (int i = 0; i < 8; ++i) r[i] = (short)f2bf(p[i * 64]);
            b2f[s][n] = r;
        }
    float4 b1v[4];                      // bias for acc1[m]: rows hid0+16m+4lg+r
    #pragma unroll
    for (int m = 0; m < 4; ++m)
        b1v[m] = *(const float4*)(b1 + w_h * 64 + 16 * m + 4 * lg);
    float b2v[2];                       // bias for acc2 cols out0+16n+l15
    #pragma unroll
    for (int n = 0; n < 2; ++n) b2v[n] = b2[w_h * 32 + 16 * n + l15];

    for (int tile = bslot; tile < NTILES; tile += BPG) {
        const int ebase = tile * TILE;
        __syncthreads();                              // prev-iter LDS reads done
        if (tid < 64) {
            srow[tid] = ei[ebase + tid];
            scol[tid] = ei[EE + ebase + tid];
        }
        __syncthreads();

        // ---- gather: e_lds[edge][k], bf16, swizzled ----
        #pragma unroll
        for (int it = 0; it < 8; ++it) {
            int idx = tid + 256 * it;
            int e = idx & 63;                          // == lane
            int c = idx >> 6;                          // 0..31 (wave-uniform)
            int r = srow[e];
            float4 v;
            if (c < 16) {
                v = ((const float4*)(x1 + (size_t)r * 64))[c];
            } else {
                float4 a = ((const float4*)(x1 + (size_t)r * 64))[c - 16];
                float4 b = ((const float4*)(xc + (size_t)scol[e] * 64))[c - 16];
                v = make_float4(b.x - a.x, b.y - a.y, b.z - a.z, b.w - a.w);
            }
            int sidx = (e * 128 + 4 * c) ^ ((e & 7) << 3);
            uint2 w; w.x = pk2(v.x, v.y); w.y = pk2(v.z, v.w);
            *(uint2*)&e_lds[sidx] = w;
        }
        __syncthreads();

        // ---- layer 1: D1[hid][edge] = W1T x e^T (+b1), relu -> h_lds ----
        f32x4 acc1[4][2];
        #pragma unroll
        for (int m = 0; m < 4; ++m)
            #pragma unroll
            for (int n = 0; n < 2; ++n) {
                acc1[m][n][0] = b1v[m].x; acc1[m][n][1] = b1v[m].y;
                acc1[m][n][2] = b1v[m].z; acc1[m][n][3] = b1v[m].w;
            }
        #pragma unroll
        for (int s = 0; s < 4; ++s) {
            bf16x8 eb[2];
            #pragma unroll
            for (int n = 0; n < 2; ++n) {
                int e = w_e * 32 + 16 * n + l15;
                int sidx = (e * 128 + 32 * s + 8 * lg) ^ ((e & 7) << 3);
                eb[n] = *(const bf16x8*)&e_lds[sidx];
            }
            #pragma unroll
            for (int m = 0; m < 4; ++m)
                #pragma unroll
                for (int n = 0; n < 2; ++n)
                    acc1[m][n] = __builtin_amdgcn_mfma_f32_16x16x32_bf16(
                        a1[m][s], eb[n], acc1[m][n], 0, 0, 0);
        }
        __syncthreads();                 // all e_lds reads done (h_lds reuse ok)
        #pragma unroll
        for (int m = 0; m < 4; ++m)
            #pragma unroll
            for (int n = 0; n < 2; ++n) {
                f32x4 v = acc1[m][n];
                float r0 = fmaxf(v[0], 0.f), r1 = fmaxf(v[1], 0.f);
                float r2 = fmaxf(v[2], 0.f), r3 = fmaxf(v[3], 0.f);
                int e = w_e * 32 + 16 * n + l15;
                int hidc = w_h * 64 + 16 * m + 4 * lg;
                int sidx = (e * 128 + hidc) ^ ((e & 7) << 3);
                uint2 w; w.x = pk2(r0, r1); w.y = pk2(r2, r3);
                *(uint2*)&h_lds[sidx] = w;
            }
        __syncthreads();

        // ---- layer 2: D2[edge][out] = h x W2 (+b2) ----
        f32x4 acc2[2][2];
        #pragma unroll
        for (int m = 0; m < 2; ++m)
            #pragma unroll
            for (int n = 0; n < 2; ++n) {
                acc2[m][n][0] = b2v[n]; acc2[m][n][1] = b2v[n];
                acc2[m][n][2] = b2v[n]; acc2[m][n][3] = b2v[n];
            }
        #pragma unroll
        for (int s = 0; s < 4; ++s) {
            bf16x8 ha[2];
            #pragma unroll
            for (int m = 0; m < 2; ++m) {
                int e = w_e * 32 + 16 * m + l15;
                int sidx = (e * 128 + 32 * s + 8 * lg) ^ ((e & 7) << 3);
                ha[m] = *(const bf16x8*)&h_lds[sidx];
            }
            #pragma unroll
            for (int m = 0; m < 2; ++m)
                #pragma unroll
                for (int n = 0; n < 2; ++n)
                    acc2[m][n] = __builtin_amdgcn_mfma_f32_16x16x32_bf16(
                        ha[m], b2f[s][n], acc2[m][n], 0, 0, 0);
        }

        // ---- scatter-max ----
        #pragma unroll
        for (int m = 0; m < 2; ++m) {
            int4 rows = *(const int4*)&srow[w_e * 32 + 16 * m + 4 * lg];
            #pragma unroll
            for (int n = 0; n < 2; ++n) {
                int outc = w_h * 32 + 16 * n + l15;
                atomicMax(&acc[(size_t)rows.x * 128 + goff + outc], enc(acc2[m][n][0]));
                atomicMax(&acc[(size_t)rows.y * 128 + goff + outc], enc(acc2[m][n][1]));
                atomicMax(&acc[(size_t)rows.z * 128 + goff + outc], enc(acc2[m][n][2]));
                atomicMax(&acc[(size_t)rows.w * 128 + goff + outc], enc(acc2[m][n][3]));
            }
        }
    }
}

extern "C" void kernel_launch(void* const* d_in, const int* in_sizes, int n_in,
                              void* d_out, int out_size, void* d_ws, size_t ws_size,
                              hipStream_t stream) {
    const float* x1 = (const float*)d_in[0];
    const float* x2 = (const float*)d_in[1];
    const int*   ei1 = (const int*)d_in[2];
    const int*   ei2 = (const int*)d_in[3];
    const float* W1 = (const float*)d_in[4];
    const float* b1 = (const float*)d_in[5];
    const float* W2 = (const float*)d_in[6];
    const float* b2 = (const float*)d_in[7];
    unsigned* acc = (unsigned*)d_out;   // accumulate in-place in d_out as u32

    const int total = NN * 128;
    hipLaunchKernelGGL(init_acc, dim3((total + 255) / 256), dim3(256), 0, stream,
                       acc, total);
    hipLaunchKernelGGL(edge_mlp, dim3(2 * BPG), dim3(256), 0, stream,
                       x1, x2, ei1, ei2, W1, b1, W2, b2, acc);
    hipLaunchKernelGGL(decode_acc, dim3((total + 255) / 256), dim3(256), 0, stream,
                       acc, total);
}

// Round 4
// 306.840 us; speedup vs baseline: 5.8405x; 1.2599x over previous
//
#include <hip/hip_runtime.h>

#define NN 50000
#define EE 800000
#define NTILES 12500
#define BPG 512                     // blocks per graph

typedef __attribute__((ext_vector_type(8))) short bf16x8;
typedef __attribute__((ext_vector_type(4))) float f32x4;
typedef __attribute__((ext_vector_type(4))) unsigned u32x4;

// order-preserving float->u32 encoding for atomicMax scatter-max
__device__ __forceinline__ unsigned enc(float f) {
    unsigned u = __float_as_uint(f);
    return u ^ (unsigned)(((int)u >> 31) | 0x80000000);   // 2 VALU ops
}
__device__ __forceinline__ float dec(unsigned u) {
    unsigned v = (u & 0x80000000u) ? (u & 0x7FFFFFFFu) : ~u;
    return __uint_as_float(v);
}
__device__ __forceinline__ unsigned short f2bf(float f) {   // RNE bf16
    unsigned u = __float_as_uint(f);
    u += 0x7fffu + ((u >> 16) & 1u);
    return (unsigned short)(u >> 16);
}
__device__ __forceinline__ unsigned pk2(float a, float b) { // [bf(a) | bf(b)<<16]
    return (unsigned)f2bf(a) | ((unsigned)f2bf(b) << 16);
}

__global__ void init_acc(unsigned* __restrict__ acc, int n) {
    int i = blockIdx.x * blockDim.x + threadIdx.x;
    if (i < n) acc[i] = 0u;   // 0 < enc(any finite float); marks "empty"
}

__global__ void decode_acc(unsigned* __restrict__ acc, int n) {
    int i = blockIdx.x * blockDim.x + threadIdx.x;
    if (i < n) {
        unsigned u = acc[i];
        ((float*)acc)[i] = (u == 0u) ? 0.0f : dec(u);   // empty -> 0.0 (ref)
    }
}

// 256 threads = 4 waves. Wave (w_h, w_e). Raw s_barrier (2/tile) + register
// prefetch of next tile's gather so global latency hides under MFMA+atomics.
__global__ __launch_bounds__(256, 2)
void edge_mlp(const float* __restrict__ x1, const float* __restrict__ x2,
              const int* __restrict__ ei1, const int* __restrict__ ei2,
              const float* __restrict__ W1, const float* __restrict__ b1,
              const float* __restrict__ W2, const float* __restrict__ b2,
              unsigned* __restrict__ acc)
{
    __shared__ short e_lds[64 * 128];   // 16 KB, (e&15) XOR-swizzled
    __shared__ short h_lds[64 * 128];   // 16 KB, same swizzle
    __shared__ int   srow[2][64];       // double-buffered (A(t+1) vs F(t) race)

    const int tid  = threadIdx.x;
    const int lane = tid & 63;
    const int l15  = lane & 15;
    const int lg   = lane >> 4;
    const int wid  = tid >> 6;
    const int w_h  = wid & 1;
    const int w_e  = wid >> 1;

    const int g     = (blockIdx.x >= BPG) ? 1 : 0;
    const int bslot = blockIdx.x & (BPG - 1);
    const int* __restrict__ ei = g ? ei2 : ei1;
    const float* __restrict__ xc = g ? x2 : x1;
    const int goff = g * 64;

    // ---- persistent register weights (identical layout to round 2) ----
    bf16x8 a1[4][4];                    // W1^T A-frags [m: hid][s: kstep]
    #pragma unroll
    for (int m = 0; m < 4; ++m)
        #pragma unroll
        for (int s = 0; s < 4; ++s) {
            const float* p = W1 + (size_t)(32 * s + 8 * lg) * 128
                               + (w_h * 64 + 16 * m + l15);
            bf16x8 r;
            #pragma unroll
            for (int i = 0; i < 8; ++i) r[i] = (short)f2bf(p[i * 128]);
            a1[m][s] = r;
        }
    bf16x8 b2f[4][2];                   // W2 B-frags [s: kstep][n: out]
    #pragma unroll
    for (int s = 0; s < 4; ++s)
        #pragma unroll
        for (int n = 0; n < 2; ++n) {
            const float* p = W2 + (size_t)(32 * s + 8 * lg) * 64
                               + (w_h * 32 + 16 * n + l15);
            bf16x8 r;
            #pragma unroll
            for (int i = 0; i < 8; ++i) r[i] = (short)f2bf(p[i * 64]);
            b2f[s][n] = r;
        }
    float4 b1v[4];
    #pragma unroll
    for (int m = 0; m < 4; ++m)
        b1v[m] = *(const float4*)(b1 + w_h * 64 + 16 * m + 4 * lg);
    float b2v[2];
    #pragma unroll
    for (int n = 0; n < 2; ++n) b2v[n] = b2[w_h * 32 + 16 * n + l15];

    // ---- gather mapping: this thread owns edge ge, float cols 16*gq..+15 ----
    const int ge = lane;
    const int gq = wid;                 // column quarter
    const int swz = (ge & 15) << 3;     // XOR swizzle, in shorts (bits 3..6)

    // ---- prologue: idx(t0), idx(t1), issue gather(t0) ----
    int rcur, ccur, rnext, cnext;
    {
        int ta = bslot;
        rcur = ei[ta * 64 + ge];
        ccur = ei[EE + ta * 64 + ge];
        int tb = ta + BPG; if (tb >= NTILES) tb = NTILES - 1;
        rnext = ei[tb * 64 + ge];
        cnext = ei[EE + tb * 64 + ge];
    }
    float4 gp0, gp1, gp2, gp3, gq0, gq1, gq2, gq3;
    {
        const float4* pp = (const float4*)(x1 + (size_t)rcur * 64 + 16 * gq);
        const float4* pq = (const float4*)(xc + (size_t)ccur * 64 + 16 * gq);
        gp0 = pp[0]; gp1 = pp[1]; gp2 = pp[2]; gp3 = pp[3];
        gq0 = pq[0]; gq1 = pq[1]; gq2 = pq[2]; gq3 = pq[3];
    }

    int i = 0;
    for (int t = bslot; t < NTILES; t += BPG, ++i) {
        // ---- A: write e tile (t) from prefetched regs; srow ----
        if (tid < 64) srow[i & 1][tid] = rcur;
        {
            short* erow = &e_lds[ge * 128];
            u32x4 v;
            v[0] = pk2(gp0.x, gp0.y); v[1] = pk2(gp0.z, gp0.w);
            v[2] = pk2(gp1.x, gp1.y); v[3] = pk2(gp1.z, gp1.w);
            *(u32x4*)&erow[(16 * gq) ^ swz] = v;
            v[0] = pk2(gp2.x, gp2.y); v[1] = pk2(gp2.z, gp2.w);
            v[2] = pk2(gp3.x, gp3.y); v[3] = pk2(gp3.z, gp3.w);
            *(u32x4*)&erow[(16 * gq + 8) ^ swz] = v;
            v[0] = pk2(gq0.x - gp0.x, gq0.y - gp0.y);
            v[1] = pk2(gq0.z - gp0.z, gq0.w - gp0.w);
            v[2] = pk2(gq1.x - gp1.x, gq1.y - gp1.y);
            v[3] = pk2(gq1.z - gp1.z, gq1.w - gp1.w);
            *(u32x4*)&erow[(64 + 16 * gq) ^ swz] = v;
            v[0] = pk2(gq2.x - gp2.x, gq2.y - gp2.y);
            v[1] = pk2(gq2.z - gp2.z, gq2.w - gp2.w);
            v[2] = pk2(gq3.x - gp3.x, gq3.y - gp3.y);
            v[3] = pk2(gq3.z - gp3.z, gq3.w - gp3.w);
            *(u32x4*)&erow[(64 + 16 * gq + 8) ^ swz] = v;
        }

        // ---- B: rotate idx; prefetch idx(t+2); issue gather(t+1) ----
        rcur = rnext; ccur = cnext;
        {
            int t2 = t + 2 * BPG; if (t2 >= NTILES) t2 = NTILES - 1;
            rnext = ei[t2 * 64 + ge];
            cnext = ei[EE + t2 * 64 + ge];
        }
        if (t + BPG < NTILES) {
            const float4* pp = (const float4*)(x1 + (size_t)rcur * 64 + 16 * gq);
            const float4* pq = (const float4*)(xc + (size_t)ccur * 64 + 16 * gq);
            gp0 = pp[0]; gp1 = pp[1]; gp2 = pp[2]; gp3 = pp[3];
            gq0 = pq[0]; gq1 = pq[1]; gq2 = pq[2]; gq3 = pq[3];
        }

        // ---- C: LDS visible, raw barrier (no vmcnt drain!) ----
        asm volatile("s_waitcnt lgkmcnt(0)\n\ts_barrier" ::: "memory");

        // ---- D: layer 1 MFMA, relu, h write ----
        f32x4 acc1[4][2];
        #pragma unroll
        for (int m = 0; m < 4; ++m)
            #pragma unroll
            for (int n = 0; n < 2; ++n) {
                acc1[m][n][0] = b1v[m].x; acc1[m][n][1] = b1v[m].y;
                acc1[m][n][2] = b1v[m].z; acc1[m][n][3] = b1v[m].w;
            }
        #pragma unroll
        for (int s = 0; s < 4; ++s) {
            bf16x8 eb[2];
            #pragma unroll
            for (int n = 0; n < 2; ++n) {
                int e = w_e * 32 + 16 * n + l15;
                int sidx = e * 128 + ((32 * s + 8 * lg) ^ ((e & 15) << 3));
                eb[n] = *(const bf16x8*)&e_lds[sidx];
            }
            #pragma unroll
            for (int m = 0; m < 4; ++m)
                #pragma unroll
                for (int n = 0; n < 2; ++n)
                    acc1[m][n] = __builtin_amdgcn_mfma_f32_16x16x32_bf16(
                        a1[m][s], eb[n], acc1[m][n], 0, 0, 0);
        }
        #pragma unroll
        for (int m = 0; m < 4; ++m)
            #pragma unroll
            for (int n = 0; n < 2; ++n) {
                f32x4 vv = acc1[m][n];
                int e = w_e * 32 + 16 * n + l15;
                int hidc = w_h * 64 + 16 * m + 4 * lg;
                int sidx = e * 128 + (hidc ^ ((e & 15) << 3));
                uint2 w;
                w.x = pk2(fmaxf(vv[0], 0.f), fmaxf(vv[1], 0.f));
                w.y = pk2(fmaxf(vv[2], 0.f), fmaxf(vv[3], 0.f));
                *(uint2*)&h_lds[sidx] = w;
            }

        // ---- E: h visible, raw barrier ----
        asm volatile("s_waitcnt lgkmcnt(0)\n\ts_barrier" ::: "memory");

        // ---- F: layer 2 MFMA + scatter-max ----
        f32x4 acc2[2][2];
        #pragma unroll
        for (int m = 0; m < 2; ++m)
            #pragma unroll
            for (int n = 0; n < 2; ++n) {
                acc2[m][n][0] = b2v[n]; acc2[m][n][1] = b2v[n];
                acc2[m][n][2] = b2v[n]; acc2[m][n][3] = b2v[n];
            }
        #pragma unroll
        for (int s = 0; s < 4; ++s) {
            bf16x8 ha[2];
            #pragma unroll
            for (int m = 0; m < 2; ++m) {
                int e = w_e * 32 + 16 * m + l15;
                int sidx = e * 128 + ((32 * s + 8 * lg) ^ ((e & 15) << 3));
                ha[m] = *(const bf16x8*)&h_lds[sidx];
            }
            #pragma unroll
            for (int m = 0; m < 2; ++m)
                #pragma unroll
                for (int n = 0; n < 2; ++n)
                    acc2[m][n] = __builtin_amdgcn_mfma_f32_16x16x32_bf16(
                        ha[m], b2f[s][n], acc2[m][n], 0, 0, 0);
        }
        #pragma unroll
        for (int m = 0; m < 2; ++m) {
            int4 rows = *(const int4*)&srow[i & 1][w_e * 32 + 16 * m + 4 * lg];
            #pragma unroll
            for (int n = 0; n < 2; ++n) {
                int outc = w_h * 32 + 16 * n + l15;
                atomicMax(&acc[(size_t)rows.x * 128 + goff + outc], enc(acc2[m][n][0]));
                atomicMax(&acc[(size_t)rows.y * 128 + goff + outc], enc(acc2[m][n][1]));
                atomicMax(&acc[(size_t)rows.z * 128 + goff + outc], enc(acc2[m][n][2]));
                atomicMax(&acc[(size_t)rows.w * 128 + goff + outc], enc(acc2[m][n][3]));
            }
        }
    }
}

extern "C" void kernel_launch(void* const* d_in, const int* in_sizes, int n_in,
                              void* d_out, int out_size, void* d_ws, size_t ws_size,
                              hipStream_t stream) {
    const float* x1 = (const float*)d_in[0];
    const float* x2 = (const float*)d_in[1];
    const int*   ei1 = (const int*)d_in[2];
    const int*   ei2 = (const int*)d_in[3];
    const float* W1 = (const float*)d_in[4];
    const float* b1 = (const float*)d_in[5];
    const float* W2 = (const float*)d_in[6];
    const float* b2 = (const float*)d_in[7];
    unsigned* acc = (unsigned*)d_out;

    const int total = NN * 128;
    hipLaunchKernelGGL(init_acc, dim3((total + 255) / 256), dim3(256), 0, stream,
                       acc, total);
    hipLaunchKernelGGL(edge_mlp, dim3(2 * BPG), dim3(256), 0, stream,
                       x1, x2, ei1, ei2, W1, b1, W2, b2, acc);
    hipLaunchKernelGGL(decode_acc, dim3((total + 255) / 256), dim3(256), 0, stream,
                       acc, total);
}

// Round 5
// 305.347 us; speedup vs baseline: 5.8691x; 1.0049x over previous
//
#include <hip/hip_runtime.h>
#include <hip/hip_bf16.h>

#define NN 50000
#define EE 800000
#define NTILES 12500
#define BPG 512                     // blocks per graph

typedef __attribute__((ext_vector_type(8))) short bf16x8;
typedef __attribute__((ext_vector_type(4))) float f32x4;
typedef __attribute__((ext_vector_type(4))) unsigned u32x4;

// order-preserving float->u32 encoding for atomicMax scatter-max
__device__ __forceinline__ unsigned enc(float f) {
    unsigned u = __float_as_uint(f);
    return u ^ (unsigned)(((int)u >> 31) | 0x80000000);   // 2 VALU ops
}
__device__ __forceinline__ float dec(unsigned u) {
    unsigned v = (u & 0x80000000u) ? (u & 0x7FFFFFFFu) : ~u;
    return __uint_as_float(v);
}
__device__ __forceinline__ unsigned short f2bf(float f) {   // RNE bf16 (weights, cold path)
    unsigned u = __float_as_uint(f);
    u += 0x7fffu + ((u >> 16) & 1u);
    return (unsigned short)(u >> 16);
}
__device__ __forceinline__ unsigned pk2(float a, float b) { // v_cvt_pk_bf16_f32
    __hip_bfloat162 t = __float22bfloat162_rn(make_float2(a, b));
    unsigned r;
    __builtin_memcpy(&r, &t, 4);
    return r;
}

__global__ void init_acc(unsigned* __restrict__ acc, int n) {
    int i = blockIdx.x * blockDim.x + threadIdx.x;
    if (i < n) acc[i] = 0u;   // 0 < enc(any finite float); marks "empty"
}

__global__ void decode_acc(unsigned* __restrict__ acc, int n) {
    int i = blockIdx.x * blockDim.x + threadIdx.x;
    if (i < n) {
        unsigned u = acc[i];
        ((float*)acc)[i] = (u == 0u) ? 0.0f : dec(u);   // empty -> 0.0 (ref)
    }
}

// 256 threads = 4 waves. Wave (w_h, w_e). Raw s_barrier (2/tile) + register
// prefetch of next tile's gather so global latency hides under MFMA+atomics.
__global__ __launch_bounds__(256, 2)
void edge_mlp(const float* __restrict__ x1, const float* __restrict__ x2,
              const int* __restrict__ ei1, const int* __restrict__ ei2,
              const float* __restrict__ W1, const float* __restrict__ b1,
              const float* __restrict__ W2, const float* __restrict__ b2,
              unsigned* __restrict__ acc)
{
    __shared__ short e_lds[64 * 128];   // 16 KB, (e&15) XOR-swizzled
    __shared__ short h_lds[64 * 128];   // 16 KB, same swizzle
    __shared__ int   srow[2][64];       // double-buffered (A(t+1) vs F(t) race)

    const int tid  = threadIdx.x;
    const int lane = tid & 63;
    const int l15  = lane & 15;
    const int lg   = lane >> 4;
    const int wid  = tid >> 6;
    const int w_h  = wid & 1;
    const int w_e  = wid >> 1;

    const int g     = (blockIdx.x >= BPG) ? 1 : 0;
    const int bslot = blockIdx.x & (BPG - 1);
    const int* __restrict__ ei = g ? ei2 : ei1;
    const float* __restrict__ xc = g ? x2 : x1;
    const int goff = g * 64;

    // ---- persistent register weights ----
    bf16x8 a1[4][4];                    // W1^T A-frags [m: hid][s: kstep]
    #pragma unroll
    for (int m = 0; m < 4; ++m)
        #pragma unroll
        for (int s = 0; s < 4; ++s) {
            const float* p = W1 + (size_t)(32 * s + 8 * lg) * 128
                               + (w_h * 64 + 16 * m + l15);
            bf16x8 r;
            #pragma unroll
            for (int i = 0; i < 8; ++i) r[i] = (short)f2bf(p[i * 128]);
            a1[m][s] = r;
        }
    bf16x8 b2f[4][2];                   // W2 B-frags [s: kstep][n: out]
    #pragma unroll
    for (int s = 0; s < 4; ++s)
        #pragma unroll
        for (int n = 0; n < 2; ++n) {
            const float* p = W2 + (size_t)(32 * s + 8 * lg) * 64
                               + (w_h * 32 + 16 * n + l15);
            bf16x8 r;
            #pragma unroll
            for (int i = 0; i < 8; ++i) r[i] = (short)f2bf(p[i * 64]);
            b2f[s][n] = r;
        }
    float4 b1v[4];
    #pragma unroll
    for (int m = 0; m < 4; ++m)
        b1v[m] = *(const float4*)(b1 + w_h * 64 + 16 * m + 4 * lg);
    float b2v[2];
    #pragma unroll
    for (int n = 0; n < 2; ++n) b2v[n] = b2[w_h * 32 + 16 * n + l15];

    // ---- gather mapping: this thread owns edge ge, float cols 16*gq..+15 ----
    const int ge = lane;
    const int gq = wid;                 // column quarter
    const int swz = (ge & 15) << 3;     // XOR swizzle, in shorts (bits 3..6)

    // ---- prologue: idx(t0), idx(t1), issue gather(t0) ----
    int rcur, ccur, rnext, cnext;
    {
        int ta = bslot;
        rcur = ei[ta * 64 + ge];
        ccur = ei[EE + ta * 64 + ge];
        int tb = ta + BPG; if (tb >= NTILES) tb = NTILES - 1;
        rnext = ei[tb * 64 + ge];
        cnext = ei[EE + tb * 64 + ge];
    }
    float4 gp0, gp1, gp2, gp3, gq0, gq1, gq2, gq3;
    {
        const float4* pp = (const float4*)(x1 + (size_t)rcur * 64 + 16 * gq);
        const float4* pq = (const float4*)(xc + (size_t)ccur * 64 + 16 * gq);
        gp0 = pp[0]; gp1 = pp[1]; gp2 = pp[2]; gp3 = pp[3];
        gq0 = pq[0]; gq1 = pq[1]; gq2 = pq[2]; gq3 = pq[3];
    }

    int i = 0;
    for (int t = bslot; t < NTILES; t += BPG, ++i) {
        // ---- A: write e tile (t) from prefetched regs; srow ----
        if (tid < 64) srow[i & 1][tid] = rcur;
        {
            short* erow = &e_lds[ge * 128];
            u32x4 v;
            v[0] = pk2(gp0.x, gp0.y); v[1] = pk2(gp0.z, gp0.w);
            v[2] = pk2(gp1.x, gp1.y); v[3] = pk2(gp1.z, gp1.w);
            *(u32x4*)&erow[(16 * gq) ^ swz] = v;
            v[0] = pk2(gp2.x, gp2.y); v[1] = pk2(gp2.z, gp2.w);
            v[2] = pk2(gp3.x, gp3.y); v[3] = pk2(gp3.z, gp3.w);
            *(u32x4*)&erow[(16 * gq + 8) ^ swz] = v;
            v[0] = pk2(gq0.x - gp0.x, gq0.y - gp0.y);
            v[1] = pk2(gq0.z - gp0.z, gq0.w - gp0.w);
            v[2] = pk2(gq1.x - gp1.x, gq1.y - gp1.y);
            v[3] = pk2(gq1.z - gp1.z, gq1.w - gp1.w);
            *(u32x4*)&erow[(64 + 16 * gq) ^ swz] = v;
            v[0] = pk2(gq2.x - gp2.x, gq2.y - gp2.y);
            v[1] = pk2(gq2.z - gp2.z, gq2.w - gp2.w);
            v[2] = pk2(gq3.x - gp3.x, gq3.y - gp3.y);
            v[3] = pk2(gq3.z - gp3.z, gq3.w - gp3.w);
            *(u32x4*)&erow[(64 + 16 * gq + 8) ^ swz] = v;
        }

        // ---- B: rotate idx; prefetch idx(t+2); issue gather(t+1) ----
        rcur = rnext; ccur = cnext;
        {
            int t2 = t + 2 * BPG; if (t2 >= NTILES) t2 = NTILES - 1;
            rnext = ei[t2 * 64 + ge];
            cnext = ei[EE + t2 * 64 + ge];
        }
        if (t + BPG < NTILES) {
            const float4* pp = (const float4*)(x1 + (size_t)rcur * 64 + 16 * gq);
            const float4* pq = (const float4*)(xc + (size_t)ccur * 64 + 16 * gq);
            gp0 = pp[0]; gp1 = pp[1]; gp2 = pp[2]; gp3 = pp[3];
            gq0 = pq[0]; gq1 = pq[1]; gq2 = pq[2]; gq3 = pq[3];
        }

        // ---- C: LDS visible, raw barrier (no vmcnt drain!) ----
        asm volatile("s_waitcnt lgkmcnt(0)\n\ts_barrier" ::: "memory");

        // ---- D: layer 1 MFMA, relu, h write ----
        f32x4 acc1[4][2];
        #pragma unroll
        for (int m = 0; m < 4; ++m)
            #pragma unroll
            for (int n = 0; n < 2; ++n) {
                acc1[m][n][0] = b1v[m].x; acc1[m][n][1] = b1v[m].y;
                acc1[m][n][2] = b1v[m].z; acc1[m][n][3] = b1v[m].w;
            }
        __builtin_amdgcn_s_setprio(1);
        #pragma unroll
        for (int s = 0; s < 4; ++s) {
            bf16x8 eb[2];
            #pragma unroll
            for (int n = 0; n < 2; ++n) {
                int e = w_e * 32 + 16 * n + l15;
                int sidx = e * 128 + ((32 * s + 8 * lg) ^ ((e & 15) << 3));
                eb[n] = *(const bf16x8*)&e_lds[sidx];
            }
            #pragma unroll
            for (int m = 0; m < 4; ++m)
                #pragma unroll
                for (int n = 0; n < 2; ++n)
                    acc1[m][n] = __builtin_amdgcn_mfma_f32_16x16x32_bf16(
                        a1[m][s], eb[n], acc1[m][n], 0, 0, 0);
        }
        __builtin_amdgcn_s_setprio(0);
        #pragma unroll
        for (int m = 0; m < 4; ++m)
            #pragma unroll
            for (int n = 0; n < 2; ++n) {
                f32x4 vv = acc1[m][n];
                int e = w_e * 32 + 16 * n + l15;
                int hidc = w_h * 64 + 16 * m + 4 * lg;
                int sidx = e * 128 + (hidc ^ ((e & 15) << 3));
                uint2 w;
                w.x = pk2(fmaxf(vv[0], 0.f), fmaxf(vv[1], 0.f));
                w.y = pk2(fmaxf(vv[2], 0.f), fmaxf(vv[3], 0.f));
                *(uint2*)&h_lds[sidx] = w;
            }

        // ---- E: h visible, raw barrier ----
        asm volatile("s_waitcnt lgkmcnt(0)\n\ts_barrier" ::: "memory");

        // ---- F: layer 2 MFMA + scatter-max ----
        f32x4 acc2[2][2];
        #pragma unroll
        for (int m = 0; m < 2; ++m)
            #pragma unroll
            for (int n = 0; n < 2; ++n) {
                acc2[m][n][0] = b2v[n]; acc2[m][n][1] = b2v[n];
                acc2[m][n][2] = b2v[n]; acc2[m][n][3] = b2v[n];
            }
        __builtin_amdgcn_s_setprio(1);
        #pragma unroll
        for (int s = 0; s < 4; ++s) {
            bf16x8 ha[2];
            #pragma unroll
            for (int m = 0; m < 2; ++m) {
                int e = w_e * 32 + 16 * m + l15;
                int sidx = e * 128 + ((32 * s + 8 * lg) ^ ((e & 15) << 3));
                ha[m] = *(const bf16x8*)&h_lds[sidx];
            }
            #pragma unroll
            for (int m = 0; m < 2; ++m)
                #pragma unroll
                for (int n = 0; n < 2; ++n)
                    acc2[m][n] = __builtin_amdgcn_mfma_f32_16x16x32_bf16(
                        ha[m], b2f[s][n], acc2[m][n], 0, 0, 0);
        }
        __builtin_amdgcn_s_setprio(0);
        #pragma unroll
        for (int m = 0; m < 2; ++m) {
            int4 rows = *(const int4*)&srow[i & 1][w_e * 32 + 16 * m + 4 * lg];
            #pragma unroll
            for (int n = 0; n < 2; ++n) {
                int outc = w_h * 32 + 16 * n + l15;
                atomicMax(&acc[(size_t)rows.x * 128 + goff + outc], enc(acc2[m][n][0]));
                atomicMax(&acc[(size_t)rows.y * 128 + goff + outc], enc(acc2[m][n][1]));
                atomicMax(&acc[(size_t)rows.z * 128 + goff + outc], enc(acc2[m][n][2]));
                atomicMax(&acc[(size_t)rows.w * 128 + goff + outc], enc(acc2[m][n][3]));
            }
        }
    }
}

extern "C" void kernel_launch(void* const* d_in, const int* in_sizes, int n_in,
                              void* d_out, int out_size, void* d_ws, size_t ws_size,
                              hipStream_t stream) {
    const float* x1 = (const float*)d_in[0];
    const float* x2 = (const float*)d_in[1];
    const int*   ei1 = (const int*)d_in[2];
    const int*   ei2 = (const int*)d_in[3];
    const float* W1 = (const float*)d_in[4];
    const float* b1 = (const float*)d_in[5];
    const float* W2 = (const float*)d_in[6];
    const float* b2 = (const float*)d_in[7];
    unsigned* acc = (unsigned*)d_out;

    const int total = NN * 128;
    hipLaunchKernelGGL(init_acc, dim3((total + 255) / 256), dim3(256), 0, stream,
                       acc, total);
    hipLaunchKernelGGL(edge_mlp, dim3(2 * BPG), dim3(256), 0, stream,
                       x1, x2, ei1, ei2, W1, b1, W2, b2, acc);
    hipLaunchKernelGGL(decode_acc, dim3((total + 255) / 256), dim3(256), 0, stream,
                       acc, total);
}